// Round 8
// baseline (620.023 us; speedup 1.0000x reference)
//
#include <hip/hip_runtime.h>
#include <hip/hip_bf16.h>
#include <math.h>

#define FIN 35
#define FOUT 128
#define NGRAPHS 512
#define NP 5            // feature panels (ceil(35/8))
#define PW 8            // panel width (floats) = 32 B rows
#define STRIP1 32       // nodes per block in nu1
#define STRIP2 16       // nodes per block in nu2
#define CHUNK 8192      // edges per block in hist1/scatter1
#define MAXBUCK 512     // >= ceil(N/256)

// ---------- helpers ----------
__device__ __forceinline__ unsigned int enc_f32(float f) {
    unsigned int u = __float_as_uint(f);
    return (u & 0x80000000u) ? ~u : (u | 0x80000000u);
}
__device__ __forceinline__ float dec_f32(unsigned int u) {
    unsigned int b = (u & 0x80000000u) ? (u ^ 0x80000000u) : ~u;
    return __uint_as_float(b);
}

// ---------- CSR build via two-level LDS radix partition (no global atomics) ----------

__global__ __launch_bounds__(256) void hist1_kernel(const int* __restrict__ dst,
                                                    int* __restrict__ counts,
                                                    int E, int nblk1, int nbuck) {
    __shared__ int h[MAXBUCK];
    for (int t = threadIdx.x; t < nbuck; t += 256) h[t] = 0;
    __syncthreads();
    int base = blockIdx.x * CHUNK;
    int end = min(base + CHUNK, E);
    for (int e = base + threadIdx.x; e < end; e += 256)
        atomicAdd(&h[dst[e] >> 8], 1);
    __syncthreads();
    for (int t = threadIdx.x; t < nbuck; t += 256)
        counts[t * nblk1 + blockIdx.x] = h[t];
}

__global__ void partial_reduce_kernel(const int* __restrict__ v_in, int* __restrict__ partial, int SC) {
    int i = blockIdx.x * 256 + threadIdx.x;
    int v = (i < SC) ? v_in[i] : 0;
    #pragma unroll
    for (int off = 32; off > 0; off >>= 1) v += __shfl_down(v, off, 64);
    __shared__ int w[4];
    if ((threadIdx.x & 63) == 0) w[threadIdx.x >> 6] = v;
    __syncthreads();
    if (threadIdx.x == 0) partial[blockIdx.x] = w[0] + w[1] + w[2] + w[3];
}

__global__ void scan_partials_kernel(int* __restrict__ partial, int NB) {
    __shared__ int lds[1024];
    int t = threadIdx.x;
    int v = (t < NB) ? partial[t] : 0;
    lds[t] = v;
    __syncthreads();
    for (int off = 1; off < 1024; off <<= 1) {
        int tv = (t >= off) ? lds[t - off] : 0;
        __syncthreads();
        lds[t] += tv;
        __syncthreads();
    }
    if (t < NB) partial[t] = lds[t] - v;   // exclusive
}

__global__ void scan_final_kernel(const int* __restrict__ v_in, const int* __restrict__ partial,
                                  int* __restrict__ outx, int SC) {
    __shared__ int lds[256];
    int i = blockIdx.x * 256 + threadIdx.x;
    int v = (i < SC) ? v_in[i] : 0;
    lds[threadIdx.x] = v;
    __syncthreads();
    for (int off = 1; off < 256; off <<= 1) {
        int tv = (threadIdx.x >= off) ? lds[threadIdx.x - off] : 0;
        __syncthreads();
        lds[threadIdx.x] += tv;
        __syncthreads();
    }
    int excl = lds[threadIdx.x] - v + partial[blockIdx.x];
    if (i < SC) {
        outx[i] = excl;
        if (i == SC - 1) outx[SC] = excl + v;
    }
}

__global__ __launch_bounds__(256) void scatter1_kernel(const int* __restrict__ src,
                                                       const int* __restrict__ dst,
                                                       const int* __restrict__ offs,
                                                       int* __restrict__ ebuf,
                                                       int E, int nblk1, int nbuck) {
    __shared__ int cur[MAXBUCK];
    for (int t = threadIdx.x; t < nbuck; t += 256) cur[t] = offs[t * nblk1 + blockIdx.x];
    __syncthreads();
    int base = blockIdx.x * CHUNK;
    int end = min(base + CHUNK, E);
    for (int e = base + threadIdx.x; e < end; e += 256) {
        int d = dst[e];
        int p = atomicAdd(&cur[d >> 8], 1);
        ebuf[p] = (src[e] << 8) | (d & 255);
    }
}

__global__ __launch_bounds__(256) void csr2_kernel(const int* __restrict__ ebuf,
                                                   const int* __restrict__ offs,
                                                   int* __restrict__ row_ptr,
                                                   int* __restrict__ esrc,
                                                   int E, int nblk1, int nbuck, int N) {
    __shared__ int h[256];
    __shared__ int scn[256];
    int b = blockIdx.x;
    int t = threadIdx.x;
    int bstart = offs[b * nblk1];
    int bend = (b + 1 < nbuck) ? offs[(b + 1) * nblk1] : E;

    h[t] = 0;
    __syncthreads();
    for (int k = bstart + t; k < bend; k += 256)
        atomicAdd(&h[ebuf[k] & 255], 1);
    __syncthreads();

    int v = h[t];
    scn[t] = v;
    __syncthreads();
    for (int off = 1; off < 256; off <<= 1) {
        int tv = (t >= off) ? scn[t - off] : 0;
        __syncthreads();
        scn[t] += tv;
        __syncthreads();
    }
    int excl = scn[t] - v;
    int node = (b << 8) + t;
    if (node < N) row_ptr[node] = bstart + excl;
    if (b == 0 && t == 0) row_ptr[N] = E;

    __syncthreads();
    h[t] = bstart + excl;
    __syncthreads();
    for (int k = bstart + t; k < bend; k += 256) {
        int e = ebuf[k];
        int p = atomicAdd(&h[e & 255], 1);
        esrc[p] = e >> 8;
    }
}

// ---------- repack x[N][35] -> 5 panels xp[p][N][8] (32 B rows, pad zeroed) ----------
__global__ void repack_kernel(const float* __restrict__ x, float* __restrict__ xp, int N) {
    int t = blockIdx.x * 256 + threadIdx.x;          // < N*40
    if (t >= N * (NP * PW)) return;
    int n = t / (NP * PW);
    int f = t - n * (NP * PW);
    float v = (f < FIN) ? x[(long long)n * FIN + f] : 0.0f;
    xp[((long long)(f >> 3) * N + n) * PW + (f & 7)] = v;
}

// ---------- panelized gather: sp[p][n][f] = mean over neighbors of panel[p][src][f] ----------
// One pass (= one 3.2 MB panel) per contiguous block range -> random reads stay L2-resident.
// esrc/sp traffic is non-temporal so it doesn't evict the panel from L2.
__global__ __launch_bounds__(256) void gather_panel_kernel(const float* __restrict__ panels,
                                                           const int* __restrict__ row_ptr,
                                                           const int* __restrict__ esrc,
                                                           float* __restrict__ sp,
                                                           int N, int BPP) {
    int pass = blockIdx.x / BPP;
    int t = (blockIdx.x - pass * BPP) * 256 + threadIdx.x;
    if (t >= N * PW) return;
    int n = t >> 3;
    int f = t & 7;
    const float* srcf = panels + (long long)pass * N * PW + f;
    int b = row_ptr[n];
    int e = row_ptr[n + 1];
    float a0 = 0.0f, a1 = 0.0f, a2 = 0.0f, a3 = 0.0f;
    float a4 = 0.0f, a5 = 0.0f, a6 = 0.0f, a7 = 0.0f;
    int k = b;
    for (; k + 8 <= e; k += 8) {
        int s0 = __builtin_nontemporal_load(esrc + k);
        int s1 = __builtin_nontemporal_load(esrc + k + 1);
        int s2 = __builtin_nontemporal_load(esrc + k + 2);
        int s3 = __builtin_nontemporal_load(esrc + k + 3);
        int s4 = __builtin_nontemporal_load(esrc + k + 4);
        int s5 = __builtin_nontemporal_load(esrc + k + 5);
        int s6 = __builtin_nontemporal_load(esrc + k + 6);
        int s7 = __builtin_nontemporal_load(esrc + k + 7);
        a0 += srcf[s0 << 3];
        a1 += srcf[s1 << 3];
        a2 += srcf[s2 << 3];
        a3 += srcf[s3 << 3];
        a4 += srcf[s4 << 3];
        a5 += srcf[s5 << 3];
        a6 += srcf[s6 << 3];
        a7 += srcf[s7 << 3];
    }
    for (; k < e; ++k) {
        int s0 = __builtin_nontemporal_load(esrc + k);
        a0 += srcf[s0 << 3];
    }
    float acc = ((a0 + a1) + (a2 + a3)) + ((a4 + a5) + (a6 + a7));
    __builtin_nontemporal_store(acc / (float)max(e - b, 1),
                                sp + (long long)pass * N * PW + t);
}

// ---------- nu1: h1 = relu(agg@Wl1 + bl1 + x@Wr1), all operands LDS-staged; panel output ----------
__global__ __launch_bounds__(256) void nu1_kernel(const float* __restrict__ x,
                                                  const float* __restrict__ s1p,
                                                  const float* __restrict__ Wl,
                                                  const float* __restrict__ bl,
                                                  const float* __restrict__ Wr,
                                                  float* __restrict__ h1p,
                                                  int N) {
    __shared__ float x_sh[STRIP1 * FIN];
    __shared__ float s_sh[STRIP1 * FIN];
    __shared__ float wl_sh[FIN * FIN];
    __shared__ float wr_sh[FIN * FIN];
    __shared__ float bl_sh[FIN];

    int node0 = blockIdx.x * STRIP1;
    if (node0 >= N) return;
    int nn = min(STRIP1, N - node0);
    int tot = nn * FIN;

    for (int t = threadIdx.x; t < FIN * FIN; t += 256) {
        wl_sh[t] = Wl[t];
        wr_sh[t] = Wr[t];
    }
    if (threadIdx.x < FIN) bl_sh[threadIdx.x] = bl[threadIdx.x];
    for (int t = threadIdx.x; t < tot; t += 256) {
        x_sh[t] = x[(long long)node0 * FIN + t];
        int nl = t / FIN;
        int i = t - nl * FIN;
        s_sh[t] = s1p[((long long)(i >> 3) * N + node0 + nl) * PW + (i & 7)];
    }
    __syncthreads();

    for (int t = threadIdx.x; t < tot; t += 256) {
        int nl = t / FIN;
        int j = t - nl * FIN;
        float acc = bl_sh[j];
        #pragma unroll
        for (int i = 0; i < FIN; ++i) {
            acc = fmaf(s_sh[nl * FIN + i], wl_sh[i * FIN + j], acc);
            acc = fmaf(x_sh[nl * FIN + i], wr_sh[i * FIN + j], acc);
        }
        acc = fmaxf(acc, 0.0f);
        h1p[((long long)(j >> 3) * N + node0 + nl) * PW + (j & 7)] = acc;   // panel layout only
    }
}

// ---------- nu2 + pool: h2 = agg@Wl2 + bl2 + h1@Wr2, segment-batched graph max ----------
__global__ __launch_bounds__(128) void nu2_pool_kernel(const float* __restrict__ h1p,
                                                       const float* __restrict__ s2p,
                                                       const float* __restrict__ Wl,
                                                       const float* __restrict__ bl,
                                                       const float* __restrict__ Wr,
                                                       const int* __restrict__ batch,
                                                       unsigned int* __restrict__ genc,
                                                       int N) {
    __shared__ float s_sh[STRIP2 * FIN];
    __shared__ float h_sh[STRIP2 * FIN];
    __shared__ int b_sh[STRIP2];
    int node0 = blockIdx.x * STRIP2;
    if (node0 >= N) return;
    int nn = min(STRIP2, N - node0);
    int tot = nn * FIN;

    for (int t = threadIdx.x; t < tot; t += 128) {
        int nl = t / FIN;
        int i = t - nl * FIN;
        long long pidx = ((long long)(i >> 3) * N + node0 + nl) * PW + (i & 7);
        h_sh[t] = h1p[pidx];
        s_sh[t] = s2p[pidx];
    }
    if (threadIdx.x < nn) b_sh[threadIdx.x] = batch[node0 + threadIdx.x];
    __syncthreads();

    int j = threadIdx.x;
    float wl[FIN], wr[FIN];
    #pragma unroll
    for (int i = 0; i < FIN; ++i) {
        wl[i] = Wl[i * FOUT + j];
        wr[i] = Wr[i * FOUT + j];
    }
    float blj = bl[j];

    int curg = b_sh[0];
    float m = -INFINITY;
    for (int nl = 0; nl < nn; ++nl) {
        float acc = blj;
        #pragma unroll
        for (int i = 0; i < FIN; ++i) {
            acc = fmaf(s_sh[nl * FIN + i], wl[i], acc);
            acc = fmaf(h_sh[nl * FIN + i], wr[i], acc);
        }
        int g = b_sh[nl];   // wave-uniform
        if (g != curg) {
            atomicMax(&genc[curg * FOUT + j], enc_f32(m));
            curg = g;
            m = acc;
        } else {
            m = fmaxf(m, acc);
        }
    }
    atomicMax(&genc[curg * FOUT + j], enc_f32(m));
}

// ---------- head: one block (128 threads) per graph ----------
__global__ void head_kernel(const unsigned int* __restrict__ genc,
                            const float* __restrict__ Wg1, const float* __restrict__ bg1,
                            const float* __restrict__ Wg2, const float* __restrict__ bg2,
                            const float* __restrict__ Wo,  const float* __restrict__ bo,
                            float* __restrict__ out) {
    __shared__ float a[FOUT];
    __shared__ float c[FOUT];
    __shared__ float red[2];
    int g = blockIdx.x;
    int j = threadIdx.x;

    a[j] = dec_f32(genc[g * FOUT + j]);
    __syncthreads();

    float acc = bg1[j];
    #pragma unroll 8
    for (int i = 0; i < FOUT; ++i) acc = fmaf(a[i], Wg1[i * FOUT + j], acc);
    c[j] = fmaxf(acc, 0.0f);
    __syncthreads();

    acc = bg2[j];
    #pragma unroll 8
    for (int i = 0; i < FOUT; ++i) acc = fmaf(c[i], Wg2[i * FOUT + j], acc);
    float t = fmaxf(acc, 0.0f) * Wo[j];

    #pragma unroll
    for (int off = 32; off > 0; off >>= 1) t += __shfl_down(t, off, 64);
    if ((threadIdx.x & 63) == 0) red[threadIdx.x >> 6] = t;
    __syncthreads();
    if (threadIdx.x == 0) out[g] = red[0] + red[1] + bo[0];
}

// ---------- launch ----------
extern "C" void kernel_launch(void* const* d_in, const int* in_sizes, int n_in,
                              void* d_out, int out_size, void* d_ws, size_t ws_size,
                              hipStream_t stream) {
    const float* x    = (const float*)d_in[0];
    const int*   ei   = (const int*)  d_in[1];
    const int*   batch= (const int*)  d_in[2];
    const float* Wl1  = (const float*)d_in[3];
    const float* bl1  = (const float*)d_in[4];
    const float* Wr1  = (const float*)d_in[5];
    const float* Wl2  = (const float*)d_in[6];
    const float* bl2  = (const float*)d_in[7];
    const float* Wr2  = (const float*)d_in[8];
    const float* Wg1  = (const float*)d_in[9];
    const float* bg1  = (const float*)d_in[10];
    const float* Wg2  = (const float*)d_in[11];
    const float* bg2  = (const float*)d_in[12];
    const float* Wo   = (const float*)d_in[13];
    const float* bo   = (const float*)d_in[14];
    float* out = (float*)d_out;

    const int N = in_sizes[0] / FIN;
    const int E = in_sizes[1] / 2;
    const int* src = ei;
    const int* dst = ei + E;

    const int nblk1 = (E + CHUNK - 1) / CHUNK;          // 391
    const int nbuck = (N + 255) >> 8;                   // 391 (<= MAXBUCK)
    const int SC = nbuck * nblk1;                       // 152881
    const int NB2 = (SC + 255) / 256;                   // 598 (<= 1024)

    const size_t panel_elems = (size_t)NP * N * PW;     // 4M floats = 16 MB

    // workspace layout (regionA: ebuf early, h1p later — lifetimes disjoint)
    char* ws = (char*)d_ws;
    size_t off = 0;
    auto alloc = [&](size_t bytes) { char* p = ws + off; off += (bytes + 255) & ~255ull; return p; };
    int*          counts  = (int*)alloc((size_t)SC * 4);
    int*          offs    = (int*)alloc((size_t)(SC + 1) * 4);
    int*          partial = (int*)alloc(1024 * 4);
    int*          row_ptr = (int*)alloc((size_t)(N + 1) * 4);
    int*          esrc    = (int*)alloc((size_t)E * 4);
    char*         regionA = (char*)alloc(panel_elems * 4);       // ebuf (12.8 MB) then h1p (16 MB)
    float*        xp_s2p  = (float*)alloc(panel_elems * 4);      // xp (conv1 in) then s2p (conv2 out)
    float*        s1p     = (float*)alloc(panel_elems * 4);
    unsigned int* genc    = (unsigned int*)alloc((size_t)NGRAPHS * FOUT * 4);
    int*   ebuf = (int*)regionA;
    float* h1p  = (float*)regionA;
    (void)ws_size; (void)n_in; (void)out_size;

    const int BS = 256;
    const int BPP = (N * PW + BS - 1) / BS;             // blocks per gather pass (3125)
    const int rpb = (N * NP * PW + BS - 1) / BS;        // repack blocks
    int nu1b = (N + STRIP1 - 1) / STRIP1;
    int nu2b = (N + STRIP2 - 1) / STRIP2;

    // ---- CSR build (LDS radix, no global atomics; reused by both conv layers) ----
    hipLaunchKernelGGL(hist1_kernel, dim3(nblk1), dim3(BS), 0, stream, dst, counts, E, nblk1, nbuck);
    hipLaunchKernelGGL(partial_reduce_kernel, dim3(NB2), dim3(BS), 0, stream, counts, partial, SC);
    hipLaunchKernelGGL(scan_partials_kernel, dim3(1), dim3(1024), 0, stream, partial, NB2);
    hipLaunchKernelGGL(scan_final_kernel, dim3(NB2), dim3(BS), 0, stream, counts, partial, offs, SC);
    hipLaunchKernelGGL(scatter1_kernel, dim3(nblk1), dim3(BS), 0, stream, src, dst, offs, ebuf, E, nblk1, nbuck);
    hipLaunchKernelGGL(csr2_kernel, dim3(nbuck), dim3(BS), 0, stream, ebuf, offs, row_ptr, esrc, E, nblk1, nbuck, N);

    // ---- conv1: repack -> panel gather -> LDS node update ----
    hipLaunchKernelGGL(repack_kernel, dim3(rpb), dim3(BS), 0, stream, x, xp_s2p, N);
    hipLaunchKernelGGL(gather_panel_kernel, dim3(NP * BPP), dim3(BS), 0, stream,
                       xp_s2p, row_ptr, esrc, s1p, N, BPP);
    hipLaunchKernelGGL(nu1_kernel, dim3(nu1b), dim3(BS), 0, stream,
                       x, s1p, Wl1, bl1, Wr1, h1p, N);

    // ---- conv2: panel gather over h1p -> node update + pool ----
    hipLaunchKernelGGL(gather_panel_kernel, dim3(NP * BPP), dim3(BS), 0, stream,
                       h1p, row_ptr, esrc, xp_s2p, N, BPP);
    hipMemsetAsync(genc, 0, (size_t)NGRAPHS * FOUT * 4, stream);
    hipLaunchKernelGGL(nu2_pool_kernel, dim3(nu2b), dim3(128), 0, stream,
                       h1p, xp_s2p, Wl2, bl2, Wr2, batch, genc, N);

    // ---- head ----
    hipLaunchKernelGGL(head_kernel, dim3(NGRAPHS), dim3(FOUT), 0, stream,
                       genc, Wg1, bg1, Wg2, bg2, Wo, bo, out);
}

// Round 9
// 516.975 us; speedup vs baseline: 1.1993x; 1.1993x over previous
//
#include <hip/hip_runtime.h>
#include <hip/hip_bf16.h>
#include <math.h>

#define FIN 35
#define FOUT 128
#define NGRAPHS 512
#define NP 5            // feature panels (ceil(35/8))
#define PW 8            // panel width (floats) = 32 B rows
#define STRIP1 32       // nodes per block in nu1
#define STRIP2 16       // nodes per block in nu2
#define CHUNK 8192      // edges per block in hist1/scatter1
#define MAXBUCK 512     // >= ceil(N/256)

// ---------- helpers ----------
__device__ __forceinline__ unsigned int enc_f32(float f) {
    unsigned int u = __float_as_uint(f);
    return (u & 0x80000000u) ? ~u : (u | 0x80000000u);
}
__device__ __forceinline__ float dec_f32(unsigned int u) {
    unsigned int b = (u & 0x80000000u) ? (u ^ 0x80000000u) : ~u;
    return __uint_as_float(b);
}

// ---------- CSR build via two-level LDS radix partition (no global atomics) ----------

__global__ __launch_bounds__(256) void hist1_kernel(const int* __restrict__ dst,
                                                    int* __restrict__ counts,
                                                    int E, int nblk1, int nbuck) {
    __shared__ int h[MAXBUCK];
    for (int t = threadIdx.x; t < nbuck; t += 256) h[t] = 0;
    __syncthreads();
    int base = blockIdx.x * CHUNK;
    int end = min(base + CHUNK, E);
    for (int e = base + threadIdx.x; e < end; e += 256)
        atomicAdd(&h[dst[e] >> 8], 1);
    __syncthreads();
    for (int t = threadIdx.x; t < nbuck; t += 256)
        counts[t * nblk1 + blockIdx.x] = h[t];
}

__global__ void partial_reduce_kernel(const int* __restrict__ v_in, int* __restrict__ partial, int SC) {
    int i = blockIdx.x * 256 + threadIdx.x;
    int v = (i < SC) ? v_in[i] : 0;
    #pragma unroll
    for (int off = 32; off > 0; off >>= 1) v += __shfl_down(v, off, 64);
    __shared__ int w[4];
    if ((threadIdx.x & 63) == 0) w[threadIdx.x >> 6] = v;
    __syncthreads();
    if (threadIdx.x == 0) partial[blockIdx.x] = w[0] + w[1] + w[2] + w[3];
}

__global__ void scan_partials_kernel(int* __restrict__ partial, int NB) {
    __shared__ int lds[1024];
    int t = threadIdx.x;
    int v = (t < NB) ? partial[t] : 0;
    lds[t] = v;
    __syncthreads();
    for (int off = 1; off < 1024; off <<= 1) {
        int tv = (t >= off) ? lds[t - off] : 0;
        __syncthreads();
        lds[t] += tv;
        __syncthreads();
    }
    if (t < NB) partial[t] = lds[t] - v;   // exclusive
}

__global__ void scan_final_kernel(const int* __restrict__ v_in, const int* __restrict__ partial,
                                  int* __restrict__ outx, int SC) {
    __shared__ int lds[256];
    int i = blockIdx.x * 256 + threadIdx.x;
    int v = (i < SC) ? v_in[i] : 0;
    lds[threadIdx.x] = v;
    __syncthreads();
    for (int off = 1; off < 256; off <<= 1) {
        int tv = (threadIdx.x >= off) ? lds[threadIdx.x - off] : 0;
        __syncthreads();
        lds[threadIdx.x] += tv;
        __syncthreads();
    }
    int excl = lds[threadIdx.x] - v + partial[blockIdx.x];
    if (i < SC) {
        outx[i] = excl;
        if (i == SC - 1) outx[SC] = excl + v;
    }
}

__global__ __launch_bounds__(256) void scatter1_kernel(const int* __restrict__ src,
                                                       const int* __restrict__ dst,
                                                       const int* __restrict__ offs,
                                                       int* __restrict__ ebuf,
                                                       int E, int nblk1, int nbuck) {
    __shared__ int cur[MAXBUCK];
    for (int t = threadIdx.x; t < nbuck; t += 256) cur[t] = offs[t * nblk1 + blockIdx.x];
    __syncthreads();
    int base = blockIdx.x * CHUNK;
    int end = min(base + CHUNK, E);
    for (int e = base + threadIdx.x; e < end; e += 256) {
        int d = dst[e];
        int p = atomicAdd(&cur[d >> 8], 1);
        ebuf[p] = (src[e] << 8) | (d & 255);
    }
}

__global__ __launch_bounds__(256) void csr2_kernel(const int* __restrict__ ebuf,
                                                   const int* __restrict__ offs,
                                                   int* __restrict__ row_ptr,
                                                   int* __restrict__ esrc,
                                                   int E, int nblk1, int nbuck, int N) {
    __shared__ int h[256];
    __shared__ int scn[256];
    int b = blockIdx.x;
    int t = threadIdx.x;
    int bstart = offs[b * nblk1];
    int bend = (b + 1 < nbuck) ? offs[(b + 1) * nblk1] : E;

    h[t] = 0;
    __syncthreads();
    for (int k = bstart + t; k < bend; k += 256)
        atomicAdd(&h[ebuf[k] & 255], 1);
    __syncthreads();

    int v = h[t];
    scn[t] = v;
    __syncthreads();
    for (int off = 1; off < 256; off <<= 1) {
        int tv = (t >= off) ? scn[t - off] : 0;
        __syncthreads();
        scn[t] += tv;
        __syncthreads();
    }
    int excl = scn[t] - v;
    int node = (b << 8) + t;
    if (node < N) row_ptr[node] = bstart + excl;
    if (b == 0 && t == 0) row_ptr[N] = E;

    __syncthreads();
    h[t] = bstart + excl;
    __syncthreads();
    for (int k = bstart + t; k < bend; k += 256) {
        int e = ebuf[k];
        int p = atomicAdd(&h[e & 255], 1);
        esrc[p] = e >> 8;
    }
}

// ---------- repack x[N][35] -> 5 panels xp[p][N][8] (32 B rows, pad zeroed) ----------
__global__ void repack_kernel(const float* __restrict__ x, float* __restrict__ xp, int N) {
    int t = blockIdx.x * 256 + threadIdx.x;          // < N*40
    if (t >= N * (NP * PW)) return;
    int n = t / (NP * PW);
    int f = t - n * (NP * PW);
    float v = (f < FIN) ? x[(long long)n * FIN + f] : 0.0f;
    xp[((long long)(f >> 3) * N + n) * PW + (f & 7)] = v;
}

// ---------- XCD-affinity panelized gather ----------
// Flat work space W = NP*N*PW items, pass-major. Work share q (of 8) is claimed by
// blocks with blockIdx%8==q, which the dispatcher round-robins onto XCD q (heuristic:
// affects locality only, never correctness). Each XCD walks a contiguous 5/8-panel
// slice, so at most 2 panels (6.4 MB worst-transient, ~3.2 MB steady) live per L2,
// and each panel is warmed into ~1-2 XCDs instead of all 8.
__global__ __launch_bounds__(256) void gather_panel_kernel(const float* __restrict__ panels,
                                                           const int* __restrict__ row_ptr,
                                                           const int* __restrict__ esrc,
                                                           float* __restrict__ sp,
                                                           int N, int WS) {
    int q = blockIdx.x & 7;
    int m = blockIdx.x >> 3;
    int w = q * WS + m * 256 + threadIdx.x;          // W = 40*N fits int
    if (w >= (q + 1) * WS) return;
    int NPW = N * PW;
    int pass = w / NPW;
    int t = w - pass * NPW;
    int n = t >> 3;
    int f = t & 7;
    const float* srcf = panels + (long long)pass * NPW + f;
    int b = row_ptr[n];
    int e = row_ptr[n + 1];
    float a0 = 0.0f, a1 = 0.0f, a2 = 0.0f, a3 = 0.0f;
    int k = b;
    for (; k + 4 <= e; k += 4) {
        int s0 = esrc[k], s1 = esrc[k + 1], s2 = esrc[k + 2], s3 = esrc[k + 3];
        a0 += srcf[s0 << 3];
        a1 += srcf[s1 << 3];
        a2 += srcf[s2 << 3];
        a3 += srcf[s3 << 3];
    }
    for (; k < e; ++k) a0 += srcf[esrc[k] << 3];
    float acc = (a0 + a1) + (a2 + a3);
    sp[(long long)pass * NPW + t] = acc / (float)max(e - b, 1);
}

// ---------- nu1: h1 = relu(agg@Wl1 + bl1 + x@Wr1), all operands LDS-staged; panel output ----------
__global__ __launch_bounds__(256) void nu1_kernel(const float* __restrict__ x,
                                                  const float* __restrict__ s1p,
                                                  const float* __restrict__ Wl,
                                                  const float* __restrict__ bl,
                                                  const float* __restrict__ Wr,
                                                  float* __restrict__ h1p,
                                                  int N) {
    __shared__ float x_sh[STRIP1 * FIN];
    __shared__ float s_sh[STRIP1 * FIN];
    __shared__ float wl_sh[FIN * FIN];
    __shared__ float wr_sh[FIN * FIN];
    __shared__ float bl_sh[FIN];

    int node0 = blockIdx.x * STRIP1;
    if (node0 >= N) return;
    int nn = min(STRIP1, N - node0);
    int tot = nn * FIN;

    for (int t = threadIdx.x; t < FIN * FIN; t += 256) {
        wl_sh[t] = Wl[t];
        wr_sh[t] = Wr[t];
    }
    if (threadIdx.x < FIN) bl_sh[threadIdx.x] = bl[threadIdx.x];
    for (int t = threadIdx.x; t < tot; t += 256) {
        x_sh[t] = x[(long long)node0 * FIN + t];
        int nl = t / FIN;
        int i = t - nl * FIN;
        s_sh[t] = s1p[((long long)(i >> 3) * N + node0 + nl) * PW + (i & 7)];
    }
    __syncthreads();

    for (int t = threadIdx.x; t < tot; t += 256) {
        int nl = t / FIN;
        int j = t - nl * FIN;
        float acc = bl_sh[j];
        #pragma unroll
        for (int i = 0; i < FIN; ++i) {
            acc = fmaf(s_sh[nl * FIN + i], wl_sh[i * FIN + j], acc);
            acc = fmaf(x_sh[nl * FIN + i], wr_sh[i * FIN + j], acc);
        }
        acc = fmaxf(acc, 0.0f);
        h1p[((long long)(j >> 3) * N + node0 + nl) * PW + (j & 7)] = acc;   // panel layout only
    }
}

// ---------- nu2 + pool: h2 = agg@Wl2 + bl2 + h1@Wr2, segment-batched graph max ----------
__global__ __launch_bounds__(128) void nu2_pool_kernel(const float* __restrict__ h1p,
                                                       const float* __restrict__ s2p,
                                                       const float* __restrict__ Wl,
                                                       const float* __restrict__ bl,
                                                       const float* __restrict__ Wr,
                                                       const int* __restrict__ batch,
                                                       unsigned int* __restrict__ genc,
                                                       int N) {
    __shared__ float s_sh[STRIP2 * FIN];
    __shared__ float h_sh[STRIP2 * FIN];
    __shared__ int b_sh[STRIP2];
    int node0 = blockIdx.x * STRIP2;
    if (node0 >= N) return;
    int nn = min(STRIP2, N - node0);
    int tot = nn * FIN;

    for (int t = threadIdx.x; t < tot; t += 128) {
        int nl = t / FIN;
        int i = t - nl * FIN;
        long long pidx = ((long long)(i >> 3) * N + node0 + nl) * PW + (i & 7);
        h_sh[t] = h1p[pidx];
        s_sh[t] = s2p[pidx];
    }
    if (threadIdx.x < nn) b_sh[threadIdx.x] = batch[node0 + threadIdx.x];
    __syncthreads();

    int j = threadIdx.x;
    float wl[FIN], wr[FIN];
    #pragma unroll
    for (int i = 0; i < FIN; ++i) {
        wl[i] = Wl[i * FOUT + j];
        wr[i] = Wr[i * FOUT + j];
    }
    float blj = bl[j];

    int curg = b_sh[0];
    float m = -INFINITY;
    for (int nl = 0; nl < nn; ++nl) {
        float acc = blj;
        #pragma unroll
        for (int i = 0; i < FIN; ++i) {
            acc = fmaf(s_sh[nl * FIN + i], wl[i], acc);
            acc = fmaf(h_sh[nl * FIN + i], wr[i], acc);
        }
        int g = b_sh[nl];   // wave-uniform
        if (g != curg) {
            atomicMax(&genc[curg * FOUT + j], enc_f32(m));
            curg = g;
            m = acc;
        } else {
            m = fmaxf(m, acc);
        }
    }
    atomicMax(&genc[curg * FOUT + j], enc_f32(m));
}

// ---------- head: one block (128 threads) per graph ----------
__global__ void head_kernel(const unsigned int* __restrict__ genc,
                            const float* __restrict__ Wg1, const float* __restrict__ bg1,
                            const float* __restrict__ Wg2, const float* __restrict__ bg2,
                            const float* __restrict__ Wo,  const float* __restrict__ bo,
                            float* __restrict__ out) {
    __shared__ float a[FOUT];
    __shared__ float c[FOUT];
    __shared__ float red[2];
    int g = blockIdx.x;
    int j = threadIdx.x;

    a[j] = dec_f32(genc[g * FOUT + j]);
    __syncthreads();

    float acc = bg1[j];
    #pragma unroll 8
    for (int i = 0; i < FOUT; ++i) acc = fmaf(a[i], Wg1[i * FOUT + j], acc);
    c[j] = fmaxf(acc, 0.0f);
    __syncthreads();

    acc = bg2[j];
    #pragma unroll 8
    for (int i = 0; i < FOUT; ++i) acc = fmaf(c[i], Wg2[i * FOUT + j], acc);
    float t = fmaxf(acc, 0.0f) * Wo[j];

    #pragma unroll
    for (int off = 32; off > 0; off >>= 1) t += __shfl_down(t, off, 64);
    if ((threadIdx.x & 63) == 0) red[threadIdx.x >> 6] = t;
    __syncthreads();
    if (threadIdx.x == 0) out[g] = red[0] + red[1] + bo[0];
}

// ---------- launch ----------
extern "C" void kernel_launch(void* const* d_in, const int* in_sizes, int n_in,
                              void* d_out, int out_size, void* d_ws, size_t ws_size,
                              hipStream_t stream) {
    const float* x    = (const float*)d_in[0];
    const int*   ei   = (const int*)  d_in[1];
    const int*   batch= (const int*)  d_in[2];
    const float* Wl1  = (const float*)d_in[3];
    const float* bl1  = (const float*)d_in[4];
    const float* Wr1  = (const float*)d_in[5];
    const float* Wl2  = (const float*)d_in[6];
    const float* bl2  = (const float*)d_in[7];
    const float* Wr2  = (const float*)d_in[8];
    const float* Wg1  = (const float*)d_in[9];
    const float* bg1  = (const float*)d_in[10];
    const float* Wg2  = (const float*)d_in[11];
    const float* bg2  = (const float*)d_in[12];
    const float* Wo   = (const float*)d_in[13];
    const float* bo   = (const float*)d_in[14];
    float* out = (float*)d_out;

    const int N = in_sizes[0] / FIN;
    const int E = in_sizes[1] / 2;
    const int* src = ei;
    const int* dst = ei + E;

    const int nblk1 = (E + CHUNK - 1) / CHUNK;          // 391
    const int nbuck = (N + 255) >> 8;                   // 391 (<= MAXBUCK)
    const int SC = nbuck * nblk1;                       // 152881
    const int NB2 = (SC + 255) / 256;                   // 598 (<= 1024)

    const size_t panel_elems = (size_t)NP * N * PW;     // 4M floats = 16 MB

    // workspace layout (regionA: ebuf early, h1p later — lifetimes disjoint)
    char* ws = (char*)d_ws;
    size_t off = 0;
    auto alloc = [&](size_t bytes) { char* p = ws + off; off += (bytes + 255) & ~255ull; return p; };
    int*          counts  = (int*)alloc((size_t)SC * 4);
    int*          offs    = (int*)alloc((size_t)(SC + 1) * 4);
    int*          partial = (int*)alloc(1024 * 4);
    int*          row_ptr = (int*)alloc((size_t)(N + 1) * 4);
    int*          esrc    = (int*)alloc((size_t)E * 4);
    char*         regionA = (char*)alloc(panel_elems * 4);       // ebuf (12.8 MB) then h1p (16 MB)
    float*        xp_s2p  = (float*)alloc(panel_elems * 4);      // xp (conv1 in) then s2p (conv2 out)
    float*        s1p     = (float*)alloc(panel_elems * 4);
    unsigned int* genc    = (unsigned int*)alloc((size_t)NGRAPHS * FOUT * 4);
    int*   ebuf = (int*)regionA;
    float* h1p  = (float*)regionA;
    (void)ws_size; (void)n_in; (void)out_size;

    const int BS = 256;
    const int Wtot = NP * N * PW;                        // 40*N, divisible by 8
    const int WS = Wtot / 8;                             // per-XCD work share (5*N)
    const int bpx = (WS + BS - 1) / BS;                  // blocks per XCD share
    const int rpb = (N * NP * PW + BS - 1) / BS;         // repack blocks
    int nu1b = (N + STRIP1 - 1) / STRIP1;
    int nu2b = (N + STRIP2 - 1) / STRIP2;

    // ---- CSR build (LDS radix, no global atomics; reused by both conv layers) ----
    hipLaunchKernelGGL(hist1_kernel, dim3(nblk1), dim3(BS), 0, stream, dst, counts, E, nblk1, nbuck);
    hipLaunchKernelGGL(partial_reduce_kernel, dim3(NB2), dim3(BS), 0, stream, counts, partial, SC);
    hipLaunchKernelGGL(scan_partials_kernel, dim3(1), dim3(1024), 0, stream, partial, NB2);
    hipLaunchKernelGGL(scan_final_kernel, dim3(NB2), dim3(BS), 0, stream, counts, partial, offs, SC);
    hipLaunchKernelGGL(scatter1_kernel, dim3(nblk1), dim3(BS), 0, stream, src, dst, offs, ebuf, E, nblk1, nbuck);
    hipLaunchKernelGGL(csr2_kernel, dim3(nbuck), dim3(BS), 0, stream, ebuf, offs, row_ptr, esrc, E, nblk1, nbuck, N);

    // ---- conv1: repack -> XCD-affinity panel gather -> LDS node update ----
    hipLaunchKernelGGL(repack_kernel, dim3(rpb), dim3(BS), 0, stream, x, xp_s2p, N);
    hipLaunchKernelGGL(gather_panel_kernel, dim3(8 * bpx), dim3(BS), 0, stream,
                       xp_s2p, row_ptr, esrc, s1p, N, WS);
    hipLaunchKernelGGL(nu1_kernel, dim3(nu1b), dim3(BS), 0, stream,
                       x, s1p, Wl1, bl1, Wr1, h1p, N);

    // ---- conv2: XCD-affinity panel gather over h1p -> node update + pool ----
    hipLaunchKernelGGL(gather_panel_kernel, dim3(8 * bpx), dim3(BS), 0, stream,
                       h1p, row_ptr, esrc, xp_s2p, N, WS);
    hipMemsetAsync(genc, 0, (size_t)NGRAPHS * FOUT * 4, stream);
    hipLaunchKernelGGL(nu2_pool_kernel, dim3(nu2b), dim3(128), 0, stream,
                       h1p, xp_s2p, Wl2, bl2, Wr2, batch, genc, N);

    // ---- head ----
    hipLaunchKernelGGL(head_kernel, dim3(NGRAPHS), dim3(FOUT), 0, stream,
                       genc, Wg1, bg1, Wg2, bg2, Wo, bo, out);
}